// Round 1
// baseline (997.466 us; speedup 1.0000x reference)
//
#include <hip/hip_runtime.h>
#include <hip/hip_bf16.h>

#define B_N 16384
#define D_N 512
#define K_N 2048
#define EPS_INV 20.0f   // 1/EPSILON
#define TEMP_INV 10.0f  // 1/TEMP
#define GAMMA_C 0.2f

typedef __attribute__((ext_vector_type(8))) short bf16x8;
typedef __attribute__((ext_vector_type(4))) float f32x4;
typedef unsigned short u16;

__device__ __forceinline__ float wred_sum(float v) {
#pragma unroll
  for (int o = 32; o; o >>= 1) v += __shfl_down(v, o, 64);
  return v;
}
__device__ __forceinline__ float wred_sum_all(float v) {
#pragma unroll
  for (int o = 32; o; o >>= 1) v += __shfl_xor(v, o, 64);
  return v;
}

// ---------------- row l2norm + bf16 convert ----------------
__global__ __launch_bounds__(256) void k_rownorm(const float* __restrict__ z1,
                                                 const float* __restrict__ z2,
                                                 __hip_bfloat16* __restrict__ zn1,
                                                 __hip_bfloat16* __restrict__ zn2) {
  int wid = threadIdx.x >> 6, lane = threadIdx.x & 63;
  int row = blockIdx.x * 4 + wid;  // 0..32767
  const float* z;
  __hip_bfloat16* zn;
  int r;
  if (row < B_N) { z = z1; zn = zn1; r = row; }
  else { z = z2; zn = zn2; r = row - B_N; }
  float vals[8];
  float ss = 0.f;
#pragma unroll
  for (int j = 0; j < 8; j++) {
    float x = z[(size_t)r * D_N + lane + 64 * j];
    vals[j] = x;
    ss += x * x;
  }
  ss = wred_sum_all(ss);
  float nrm = fmaxf(sqrtf(ss), 1e-12f);
  float inv = 1.0f / nrm;
#pragma unroll
  for (int j = 0; j < 8; j++)
    zn[(size_t)r * D_N + lane + 64 * j] = __float2bfloat16(vals[j] * inv);
}

// ---------------- W -> bf16 ----------------
__global__ __launch_bounds__(256) void k_convW(const float* __restrict__ W,
                                               __hip_bfloat16* __restrict__ Wb) {
  size_t base = ((size_t)blockIdx.x * 256 + threadIdx.x) * 8;
#pragma unroll
  for (int j = 0; j < 8; j++) Wb[base + j] = __float2bfloat16(W[base + j]);
}

// ---------------- per-column sum / sumsq ----------------
__global__ __launch_bounds__(512) void k_colstats(const float* __restrict__ z1,
                                                  const float* __restrict__ z2,
                                                  float* __restrict__ csum,
                                                  float* __restrict__ csumsq) {
  const float* z = blockIdx.z ? z2 : z1;
  float* s = csum + blockIdx.z * D_N;
  float* s2 = csumsq + blockIdx.z * D_N;
  int col = blockIdx.x * 64 + threadIdx.x;
  int b0 = blockIdx.y * 512 + threadIdx.y;
  float a = 0.f, a2 = 0.f;
#pragma unroll 4
  for (int u = 0; u < 64; u++) {
    float x = z[(size_t)(b0 + 8 * u) * D_N + col];
    a += x;
    a2 += x * x;
  }
  __shared__ float ls[8][64], ls2[8][64];
  ls[threadIdx.y][threadIdx.x] = a;
  ls2[threadIdx.y][threadIdx.x] = a2;
  __syncthreads();
  if (threadIdx.y == 0) {
    float t = 0.f, t2 = 0.f;
    for (int u = 0; u < 8; u++) { t += ls[u][threadIdx.x]; t2 += ls2[u][threadIdx.x]; }
    atomicAdd(&s[col], t);
    atomicAdd(&s2[col], t2);
  }
}

// ---------------- variance hinge loss ----------------
__global__ __launch_bounds__(256) void k_vloss(const float* __restrict__ csum,
                                               const float* __restrict__ csumsq,
                                               float* __restrict__ scal) {
  int idx = blockIdx.x * 256 + threadIdx.x;  // < 1024
  float s = csum[idx], sq = csumsq[idx];
  float mean = s * (1.0f / (float)B_N);
  float var = (sq - (float)B_N * mean * mean) * (1.0f / (float)(B_N - 1));
  float term = fmaxf(0.f, GAMMA_C - sqrtf(var + 1e-8f));
  term = wred_sum(term);
  __shared__ float sw[4];
  if ((threadIdx.x & 63) == 0) sw[threadIdx.x >> 6] = term;
  __syncthreads();
  if (threadIdx.x == 0) atomicAdd(&scal[0], sw[0] + sw[1] + sw[2] + sw[3]);
}

// ---------------- gram G = z^T z (split-K into 16 chunks) ----------------
__global__ __launch_bounds__(256) void k_gram(const float* __restrict__ z1,
                                              const float* __restrict__ z2,
                                              float* __restrict__ Gpart) {
  int zi = blockIdx.z >> 4, chunk = blockIdx.z & 15;
  const float* z = zi ? z2 : z1;
  float* gp = Gpart + ((size_t)(zi * 16 + chunk)) * D_N * D_N;
  int i0 = blockIdx.x * 64, j0 = blockIdx.y * 64;
  __shared__ u16 lA[64][32];
  __shared__ u16 lB[64][32];
  int t = threadIdx.x, wid = t >> 6, lane = t & 63;
  int col = t & 63, bq = t >> 6;
  f32x4 acc[4];
#pragma unroll
  for (int q = 0; q < 4; q++) acc[q] = (f32x4){0.f, 0.f, 0.f, 0.f};
  for (int bb = 0; bb < 1024; bb += 32) {
#pragma unroll
    for (int u = 0; u < 8; u++) {
      int br = bq + 4 * u;
      size_t rowbase = ((size_t)(chunk * 1024 + bb + br)) * D_N;
      __hip_bfloat16 ha = __float2bfloat16(z[rowbase + i0 + col]);
      __hip_bfloat16 hb = __float2bfloat16(z[rowbase + j0 + col]);
      lA[col][br] = __builtin_bit_cast(u16, ha);
      lB[col][br] = __builtin_bit_cast(u16, hb);
    }
    __syncthreads();
    int m = lane & 15, q = lane >> 4;
    bf16x8 a = *(const bf16x8*)&lA[16 * wid + m][8 * q];
#pragma unroll
    for (int tt = 0; tt < 4; tt++) {
      bf16x8 b = *(const bf16x8*)&lB[16 * tt + m][8 * q];
      acc[tt] = __builtin_amdgcn_mfma_f32_16x16x32_bf16(a, b, acc[tt], 0, 0, 0);
    }
    __syncthreads();
  }
  int n = lane & 15, q = lane >> 4;
#pragma unroll
  for (int tt = 0; tt < 4; tt++)
#pragma unroll
    for (int r = 0; r < 4; r++) {
      int gi = i0 + 16 * wid + q * 4 + r;
      int gj = j0 + 16 * tt + n;
      gp[(size_t)gi * D_N + gj] = acc[tt][r];
    }
}

// ---------------- covariance off-diag reduce ----------------
__global__ __launch_bounds__(256) void k_covreduce(const float* __restrict__ Gpart,
                                                   const float* __restrict__ csum,
                                                   float* __restrict__ scal) {
  int zi = blockIdx.y;
  int idx = blockIdx.x * 256 + threadIdx.x;  // < 262144
  int i = idx >> 9, j = idx & 511;
  const float* gp = Gpart + (size_t)zi * 16 * D_N * D_N;
  float g = 0.f;
#pragma unroll
  for (int c = 0; c < 16; c++) g += gp[(size_t)c * D_N * D_N + idx];
  float mi = csum[zi * D_N + i] * (1.0f / (float)B_N);
  float mj = csum[zi * D_N + j] * (1.0f / (float)B_N);
  float C = (g - (float)B_N * mi * mj) * (1.0f / (float)(B_N - 1));
  float v = (i == j) ? 0.f : C * C;
  v = wred_sum(v);
  __shared__ float sw[4];
  if ((threadIdx.x & 63) == 0) sw[threadIdx.x >> 6] = v;
  __syncthreads();
  if (threadIdx.x == 0) atomicAdd(&scal[1], sw[0] + sw[1] + sw[2] + sw[3]);
}

// ---------------- logits = zn @ W^T (bf16 MFMA, 64x64 tile) ----------------
__global__ __launch_bounds__(256) void k_logits(const __hip_bfloat16* __restrict__ zn1,
                                                const __hip_bfloat16* __restrict__ zn2,
                                                const __hip_bfloat16* __restrict__ Wb,
                                                __hip_bfloat16* __restrict__ L1,
                                                __hip_bfloat16* __restrict__ L2) {
  const u16* A = (const u16*)(blockIdx.z ? zn2 : zn1);
  __hip_bfloat16* Lout = blockIdx.z ? L2 : L1;
  const u16* Wu = (const u16*)Wb;
  int b0 = blockIdx.x * 64, k0 = blockIdx.y * 64;
  __shared__ u16 lA[64][32], lB[64][32];
  int t = threadIdx.x, wid = t >> 6, lane = t & 63;
  int lrow = t >> 2, lkoff = (t & 3) * 8;
  f32x4 acc[4];
#pragma unroll
  for (int q = 0; q < 4; q++) acc[q] = (f32x4){0.f, 0.f, 0.f, 0.f};
  for (int d0 = 0; d0 < D_N; d0 += 32) {
    *(bf16x8*)&lA[lrow][lkoff] = *(const bf16x8*)&A[(size_t)(b0 + lrow) * D_N + d0 + lkoff];
    *(bf16x8*)&lB[lrow][lkoff] = *(const bf16x8*)&Wu[(size_t)(k0 + lrow) * D_N + d0 + lkoff];
    __syncthreads();
    int m = lane & 15, q = lane >> 4;
    bf16x8 a = *(const bf16x8*)&lA[16 * wid + m][8 * q];
#pragma unroll
    for (int tt = 0; tt < 4; tt++) {
      bf16x8 b = *(const bf16x8*)&lB[16 * tt + m][8 * q];
      acc[tt] = __builtin_amdgcn_mfma_f32_16x16x32_bf16(a, b, acc[tt], 0, 0, 0);
    }
    __syncthreads();
  }
  int n = lane & 15, q = lane >> 4;
#pragma unroll
  for (int tt = 0; tt < 4; tt++)
#pragma unroll
    for (int r = 0; r < 4; r++) {
      int gb = b0 + 16 * wid + q * 4 + r;
      int gk = k0 + 16 * tt + n;
      Lout[(size_t)gb * K_N + gk] = __float2bfloat16(acc[tt][r]);
    }
}

// ---------------- sinkhorn pass A: rowsum_k = sum_b E_kb * c_b ----------------
__global__ __launch_bounds__(256) void k_passA(const __hip_bfloat16* __restrict__ L1,
                                               const __hip_bfloat16* __restrict__ L2,
                                               const float* __restrict__ colsum,
                                               float* __restrict__ rowsum, int it) {
  int zi = blockIdx.z;
  const __hip_bfloat16* L = zi ? L2 : L1;
  const float* cs = colsum + ((size_t)zi * 3 + (it > 0 ? it - 1 : 0)) * B_N;
  float* rs = rowsum + ((size_t)zi * 3 + it) * K_N;
  int k = blockIdx.x * 256 + threadIdx.x;
  int b0 = blockIdx.y * 256;
  __shared__ float cv[256];
  cv[threadIdx.x] = (it == 0) ? 1.0f : 1.0f / ((float)B_N * cs[b0 + threadIdx.x]);
  __syncthreads();
  float a = 0.f;
  for (int i = 0; i < 256; i++) {
    float x = __bfloat162float(L[(size_t)(b0 + i) * K_N + k]);
    a += __expf(EPS_INV * x) * cv[i];
  }
  atomicAdd(&rs[k], a);
}

// ---------------- sinkhorn pass B: colsum_b = sum_k E_kb * r_k ----------------
__global__ __launch_bounds__(256) void k_passB(const __hip_bfloat16* __restrict__ L1,
                                               const __hip_bfloat16* __restrict__ L2,
                                               const float* __restrict__ rowsum,
                                               float* __restrict__ colsum, int it) {
  int zi = blockIdx.y;
  const __hip_bfloat16* L = zi ? L2 : L1;
  const float* rs = rowsum + ((size_t)zi * 3 + it) * K_N;
  float* cs = colsum + ((size_t)zi * 3 + it) * B_N;
  __shared__ float r[K_N];
  __shared__ float red[4];
  int t = threadIdx.x;
  for (int k = t; k < K_N; k += 256) r[k] = 1.0f / ((float)K_N * rs[k]);
  __syncthreads();
  int b0 = blockIdx.x * 16;
  for (int rr = 0; rr < 16; rr++) {
    int b = b0 + rr;
    float a = 0.f;
#pragma unroll
    for (int j = 0; j < 8; j++) {
      int k = t + 256 * j;
      float x = __bfloat162float(L[(size_t)b * K_N + k]);
      a += __expf(EPS_INV * x) * r[k];
    }
    a = wred_sum(a);
    if ((t & 63) == 0) red[t >> 6] = a;
    __syncthreads();
    if (t == 0) cs[b] = red[0] + red[1] + red[2] + red[3];
    __syncthreads();
  }
}

// ---------------- final fused pass: CE loss + diagnostics ----------------
__global__ __launch_bounds__(256) void k_final(const __hip_bfloat16* __restrict__ L1,
                                               const __hip_bfloat16* __restrict__ L2,
                                               const float* __restrict__ rowsum,
                                               const float* __restrict__ colsum,
                                               float* __restrict__ probsum,
                                               int* __restrict__ counts,
                                               float* __restrict__ scal) {
  __shared__ float r1[K_N], r2[K_N], lr1[K_N], lr2[K_N], probs[K_N];
  __shared__ int cnt[K_N];
  __shared__ __hip_bfloat16 row1[K_N], row2[K_N];
  __shared__ float sred[4][6];
  __shared__ float sav[4][4];
  __shared__ int sai[4][4];
  __shared__ float zb[2];
  const float* rs1 = rowsum + 2 * K_N;
  const float* rs2 = rowsum + 5 * K_N;
  const float* cs1 = colsum + 2 * B_N;
  const float* cs2 = colsum + 5 * B_N;
  int t = threadIdx.x;
  for (int k = t; k < K_N; k += 256) {
    float a = 1.0f / ((float)K_N * rs1[k]);
    r1[k] = a; lr1[k] = __logf(a);
    float b = 1.0f / ((float)K_N * rs2[k]);
    r2[k] = b; lr2[k] = __logf(b);
    probs[k] = 0.f; cnt[k] = 0;
  }
  __syncthreads();
  float ce_loc = 0.f; int acc_loc = 0;
  int lane = t & 63, wid = t >> 6;
  for (int rr = 0; rr < 64; rr++) {
    int b = blockIdx.x * 64 + rr;
    *(bf16x8*)&row1[t * 8] = *(const bf16x8*)&L1[(size_t)b * K_N + t * 8];
    *(bf16x8*)&row2[t * 8] = *(const bf16x8*)&L2[(size_t)b * K_N + t * 8];
    __syncthreads();
    float sE1 = 0, sE2 = 0, d12 = 0, d21 = 0, Z1 = 0, Z2 = 0;
    float m1v = -1e30f, m2v = -1e30f, a1v = -1e30f, a2v = -1e30f;
    int m1i = 0, m2i = 0, a1i = 0, a2i = 0;
#pragma unroll
    for (int j = 0; j < 8; j++) {
      int k = t + 256 * j;
      float x1 = __bfloat162float(row1[k]);
      float x2 = __bfloat162float(row2[k]);
      float t1 = __expf(TEMP_INV * x1), t2 = __expf(TEMP_INV * x2);
      float e1 = t1 * t1 * r1[k], e2 = t2 * t2 * r2[k];
      sE1 += e1; sE2 += e2;
      d12 += e1 * (TEMP_INV * x2);
      d21 += e2 * (TEMP_INV * x1);
      Z1 += t1; Z2 += t2;
      if (x1 > m1v) { m1v = x1; m1i = k; }
      if (x2 > m2v) { m2v = x2; m2i = k; }
      float s1 = EPS_INV * x1 + lr1[k];
      if (s1 > a1v) { a1v = s1; a1i = k; }
      float s2 = EPS_INV * x2 + lr2[k];
      if (s2 > a2v) { a2v = s2; a2i = k; }
    }
#pragma unroll
    for (int o = 32; o; o >>= 1) {
      sE1 += __shfl_down(sE1, o, 64);
      sE2 += __shfl_down(sE2, o, 64);
      d12 += __shfl_down(d12, o, 64);
      d21 += __shfl_down(d21, o, 64);
      Z1 += __shfl_down(Z1, o, 64);
      Z2 += __shfl_down(Z2, o, 64);
      float ov; int oi;
      ov = __shfl_down(m1v, o, 64); oi = __shfl_down(m1i, o, 64);
      if (ov > m1v || (ov == m1v && oi < m1i)) { m1v = ov; m1i = oi; }
      ov = __shfl_down(m2v, o, 64); oi = __shfl_down(m2i, o, 64);
      if (ov > m2v || (ov == m2v && oi < m2i)) { m2v = ov; m2i = oi; }
      ov = __shfl_down(a1v, o, 64); oi = __shfl_down(a1i, o, 64);
      if (ov > a1v || (ov == a1v && oi < a1i)) { a1v = ov; a1i = oi; }
      ov = __shfl_down(a2v, o, 64); oi = __shfl_down(a2i, o, 64);
      if (ov > a2v || (ov == a2v && oi < a2i)) { a2v = ov; a2i = oi; }
    }
    if (lane == 0) {
      sred[wid][0] = sE1; sred[wid][1] = sE2; sred[wid][2] = d12;
      sred[wid][3] = d21; sred[wid][4] = Z1; sred[wid][5] = Z2;
      sav[wid][0] = m1v; sai[wid][0] = m1i;
      sav[wid][1] = m2v; sai[wid][1] = m2i;
      sav[wid][2] = a1v; sai[wid][2] = a1i;
      sav[wid][3] = a2v; sai[wid][3] = a2i;
    }
    __syncthreads();
    if (t == 0) {
      float tS[6] = {0, 0, 0, 0, 0, 0};
      for (int w = 0; w < 4; w++)
        for (int q = 0; q < 6; q++) tS[q] += sred[w][q];
      float bv[4]; int bi[4];
      for (int q = 0; q < 4; q++) {
        bv[q] = sav[0][q]; bi[q] = sai[0][q];
        for (int w = 1; w < 4; w++) {
          float ov = sav[w][q]; int oi = sai[w][q];
          if (ov > bv[q] || (ov == bv[q] && oi < bi[q])) { bv[q] = ov; bi[q] = oi; }
        }
      }
      float invc1 = 1.0f / cs1[b], invc2 = 1.0f / cs2[b];
      float logZ1 = __logf(tS[4]), logZ2 = __logf(tS[5]);
      float sumP1 = tS[0] * invc1, sumP2 = tS[1] * invc2;
      float term1 = tS[2] * invc1 - logZ2 * sumP1;
      float term2 = tS[3] * invc2 - logZ1 * sumP2;
      ce_loc += term1 + term2;
      acc_loc += (bi[0] == bi[3]) + (bi[1] == bi[2]);
      cnt[bi[0]]++;
      cnt[bi[1]]++;
      zb[0] = tS[4]; zb[1] = tS[5];
    }
    __syncthreads();
    float iZ1 = 1.0f / zb[0], iZ2 = 1.0f / zb[1];
#pragma unroll
    for (int j = 0; j < 8; j++) {
      int k = t + 256 * j;
      float x1 = __bfloat162float(row1[k]);
      float x2 = __bfloat162float(row2[k]);
      probs[k] += __expf(TEMP_INV * x1) * iZ1 + __expf(TEMP_INV * x2) * iZ2;
    }
    __syncthreads();
  }
  if (t == 0) {
    atomicAdd(&scal[2], ce_loc);
    atomicAdd(&scal[3], (float)acc_loc);
  }
  for (int k = t; k < K_N; k += 256) {
    atomicAdd(&probsum[k], probs[k]);
    atomicAdd(&counts[k], cnt[k]);
  }
}

// ---------------- combine: all 7 outputs ----------------
__global__ __launch_bounds__(256) void k_combine(const float* __restrict__ scal,
                                                 const float* __restrict__ probsum,
                                                 const int* __restrict__ counts,
                                                 float* __restrict__ out) {
  int t = threadIdx.x;
  float ec = 0.f, ep = 0.f;
  for (int k = t; k < K_N; k += 256) {
    float p = (float)counts[k] * (1.0f / (2.0f * (float)B_N));
    ec += -p * __logf(p + 1e-7f);
    float q = probsum[k] * (1.0f / (2.0f * (float)B_N));
    ep += -q * __logf(q + 1e-7f);
  }
  ec = wred_sum(ec);
  ep = wred_sum(ep);
  __shared__ float se[4], sp[4];
  if ((t & 63) == 0) { se[t >> 6] = ec; sp[t >> 6] = ep; }
  __syncthreads();
  if (t == 0) {
    float tec = se[0] + se[1] + se[2] + se[3];
    float tep = sp[0] + sp[1] + sp[2] + sp[3];
    float ce = -0.5f * scal[2] * (1.0f / (float)B_N);
    float lvar = scal[0] * (1.0f / (float)D_N);
    float lcov = scal[1] * (1.0f / (float)D_N);
    float acc = scal[3] * (1.0f / (2.0f * (float)B_N));
    out[0] = 15.0f * ce + lvar + lcov;
    out[1] = ce;
    out[2] = lvar;
    out[3] = lcov;
    out[4] = __expf(tec);
    out[5] = __expf(tep);
    out[6] = acc;
  }
}

extern "C" void kernel_launch(void* const* d_in, const int* in_sizes, int n_in,
                              void* d_out, int out_size, void* d_ws, size_t ws_size,
                              hipStream_t stream) {
  (void)in_sizes; (void)n_in; (void)out_size; (void)ws_size;
  const float* z1 = (const float*)d_in[0];
  const float* z2 = (const float*)d_in[1];
  const float* W = (const float*)d_in[2];

  char* w = (char*)d_ws;
  size_t off = 0;
  auto take = [&](size_t b) -> void* {
    void* p = w + off;
    off = (off + b + 255) & ~(size_t)255;
    return p;
  };
  float* rowsum = (float*)take(2 * 3 * K_N * 4);
  float* csum = (float*)take(2 * D_N * 4);
  float* csumsq = (float*)take(2 * D_N * 4);
  float* probsum = (float*)take(K_N * 4);
  int* counts = (int*)take(K_N * 4);
  float* scal = (float*)take(64);
  size_t zero_bytes = off;
  float* colsum = (float*)take((size_t)2 * 3 * B_N * 4);
  __hip_bfloat16* zn1 = (__hip_bfloat16*)take((size_t)B_N * D_N * 2);
  __hip_bfloat16* zn2 = (__hip_bfloat16*)take((size_t)B_N * D_N * 2);
  __hip_bfloat16* Wb = (__hip_bfloat16*)take((size_t)K_N * D_N * 2);
  __hip_bfloat16* L1 = (__hip_bfloat16*)take((size_t)B_N * K_N * 2);
  __hip_bfloat16* L2 = (__hip_bfloat16*)take((size_t)B_N * K_N * 2);
  float* Gpart = (float*)take((size_t)2 * 16 * D_N * D_N * 4);

  hipMemsetAsync(d_ws, 0, zero_bytes, stream);

  k_rownorm<<<8192, 256, 0, stream>>>(z1, z2, zn1, zn2);
  k_convW<<<512, 256, 0, stream>>>(W, Wb);
  k_colstats<<<dim3(8, 32, 2), dim3(64, 8), 0, stream>>>(z1, z2, csum, csumsq);
  k_vloss<<<4, 256, 0, stream>>>(csum, csumsq, scal);
  k_gram<<<dim3(8, 8, 32), 256, 0, stream>>>(z1, z2, Gpart);
  k_covreduce<<<dim3(1024, 2), 256, 0, stream>>>(Gpart, csum, scal);
  k_logits<<<dim3(256, 32, 2), 256, 0, stream>>>(zn1, zn2, Wb, L1, L2);
  for (int it = 0; it < 3; it++) {
    k_passA<<<dim3(8, 64, 2), 256, 0, stream>>>(L1, L2, colsum, rowsum, it);
    k_passB<<<dim3(1024, 2), 256, 0, stream>>>(L1, L2, rowsum, colsum, it);
  }
  k_final<<<256, 256, 0, stream>>>(L1, L2, rowsum, colsum, probsum, counts, scal);
  k_combine<<<1, 256, 0, stream>>>(scal, probsum, counts, (float*)d_out);
}

// Round 3
// 720.489 us; speedup vs baseline: 1.3844x; 1.3844x over previous
//
#include <hip/hip_runtime.h>
#include <hip/hip_bf16.h>

#define B_N 16384
#define D_N 512
#define K_N 2048

typedef __attribute__((ext_vector_type(8))) short bf16x8;
typedef __attribute__((ext_vector_type(4))) float f32x4;
typedef __attribute__((ext_vector_type(4))) unsigned short u16x4;
typedef unsigned short u16;

__device__ __forceinline__ float bf2f(short s) {
  return __builtin_bit_cast(float, ((unsigned)(u16)s) << 16);
}
__device__ __forceinline__ u16 f2bf(float x) {
  return __builtin_bit_cast(u16, __float2bfloat16(x));
}
__device__ __forceinline__ float wred_sum(float v) {
#pragma unroll
  for (int o = 32; o; o >>= 1) v += __shfl_down(v, o, 64);
  return v;
}

__device__ __forceinline__ void gld16(const u16* g, const u16* l) {
  __builtin_amdgcn_global_load_lds((const __attribute__((address_space(1))) void*)g,
                                   (__attribute__((address_space(3))) void*)l, 16, 0, 0);
}

// ---------------- row l2norm + bf16 convert (normalized + raw) ----------------
__global__ __launch_bounds__(256) void k_rownorm(const float* __restrict__ z1,
                                                 const float* __restrict__ z2,
                                                 u16* __restrict__ zn1, u16* __restrict__ zn2,
                                                 u16* __restrict__ zb1, u16* __restrict__ zb2) {
  int wid = threadIdx.x >> 6, lane = threadIdx.x & 63;
  int row = blockIdx.x * 4 + wid;
  const float* z; u16 *zn, *zb; int r;
  if (row < B_N) { z = z1; zn = zn1; zb = zb1; r = row; }
  else { z = z2; zn = zn2; zb = zb2; r = row - B_N; }
  const float4* zr = (const float4*)(z + (size_t)r * D_N);
  float4 va = zr[lane], vb = zr[lane + 64];
  float ss = va.x*va.x + va.y*va.y + va.z*va.z + va.w*va.w
           + vb.x*vb.x + vb.y*vb.y + vb.z*vb.z + vb.w*vb.w;
#pragma unroll
  for (int o = 32; o; o >>= 1) ss += __shfl_xor(ss, o, 64);
  float inv = 1.0f / fmaxf(sqrtf(ss), 1e-12f);
  u16x4 pa = {f2bf(va.x), f2bf(va.y), f2bf(va.z), f2bf(va.w)};
  u16x4 pb = {f2bf(vb.x), f2bf(vb.y), f2bf(vb.z), f2bf(vb.w)};
  u16x4 na = {f2bf(va.x*inv), f2bf(va.y*inv), f2bf(va.z*inv), f2bf(va.w*inv)};
  u16x4 nb = {f2bf(vb.x*inv), f2bf(vb.y*inv), f2bf(vb.z*inv), f2bf(vb.w*inv)};
  ((u16x4*)(zb + (size_t)r * D_N))[lane] = pa;
  ((u16x4*)(zb + (size_t)r * D_N))[lane + 64] = pb;
  ((u16x4*)(zn + (size_t)r * D_N))[lane] = na;
  ((u16x4*)(zn + (size_t)r * D_N))[lane + 64] = nb;
}

// ---------------- W -> bf16 ----------------
__global__ __launch_bounds__(256) void k_convW(const float* __restrict__ W,
                                               u16* __restrict__ Wb) {
  size_t base = ((size_t)blockIdx.x * 256 + threadIdx.x) * 8;
#pragma unroll
  for (int j = 0; j < 8; j++) Wb[base + j] = f2bf(W[base + j]);
}

// ---------------- per-column sum / sumsq (bf16 input) ----------------
__global__ __launch_bounds__(512) void k_colstats(const u16* __restrict__ zb1,
                                                  const u16* __restrict__ zb2,
                                                  float* __restrict__ csum,
                                                  float* __restrict__ csumsq) {
  int zi = blockIdx.z;
  const u16* z = zi ? zb2 : zb1;
  __shared__ float s1[512], s2[512];
  int t = threadIdx.y * 64 + threadIdx.x;
  s1[t] = 0.f; s2[t] = 0.f;
  __syncthreads();
  int c0 = threadIdx.x * 8;
  float a[8], a2[8];
#pragma unroll
  for (int e = 0; e < 8; e++) { a[e] = 0.f; a2[e] = 0.f; }
  for (int u = 0; u < 32; u++) {
    int r = blockIdx.y * 256 + threadIdx.y + 8 * u;
    bf16x8 v = *(const bf16x8*)&z[(size_t)r * D_N + c0];
#pragma unroll
    for (int e = 0; e < 8; e++) { float x = bf2f(v[e]); a[e] += x; a2[e] += x * x; }
  }
#pragma unroll
  for (int e = 0; e < 8; e++) {
    atomicAdd(&s1[c0 + e], a[e]);
    atomicAdd(&s2[c0 + e], a2[e]);
  }
  __syncthreads();
  atomicAdd(&csum[zi * D_N + t], s1[t]);
  atomicAdd(&csumsq[zi * D_N + t], s2[t]);
}

// ---------------- variance hinge loss ----------------
__global__ __launch_bounds__(256) void k_vloss(const float* __restrict__ csum,
                                               const float* __restrict__ csumsq,
                                               float* __restrict__ scal) {
  int idx = blockIdx.x * 256 + threadIdx.x;  // < 1024
  float s = csum[idx], sq = csumsq[idx];
  float mean = s * (1.0f / (float)B_N);
  float var = (sq - (float)B_N * mean * mean) * (1.0f / (float)(B_N - 1));
  float term = fmaxf(0.f, 0.2f - sqrtf(var + 1e-8f));
  term = wred_sum(term);
  __shared__ float sw[4];
  if ((threadIdx.x & 63) == 0) sw[threadIdx.x >> 6] = term;
  __syncthreads();
  if (threadIdx.x == 0) atomicAdd(&scal[0], sw[0] + sw[1] + sw[2] + sw[3]);
}

// ---------------- gram (bf16 input, upper-triangle tiles, split-K 16) ----------------
__global__ __launch_bounds__(256) void k_gram(const u16* __restrict__ zb1,
                                              const u16* __restrict__ zb2,
                                              float* __restrict__ Gpart) {
  int zi = blockIdx.z >> 4, chunk = blockIdx.z & 15;
  const u16* z = zi ? zb2 : zb1;
  int ti = 0, xx = blockIdx.x;
  while (xx >= 8 - ti) { xx -= 8 - ti; ti++; }
  int tj = ti + xx;
  int i0 = ti * 64, j0 = tj * 64;
  __shared__ u16 lA[64][32], lB[64][32];
  int t = threadIdx.x, wid = t >> 6, lane = t & 63;
  int br = t & 31, fg = t >> 5;
  f32x4 acc[4];
#pragma unroll
  for (int q = 0; q < 4; q++) acc[q] = (f32x4){0.f, 0.f, 0.f, 0.f};
  for (int bb = 0; bb < 1024; bb += 32) {
    size_t rb = ((size_t)chunk * 1024 + bb + br) * D_N;
    bf16x8 va = *(const bf16x8*)&z[rb + i0 + fg * 8];
    bf16x8 vb = *(const bf16x8*)&z[rb + j0 + fg * 8];
#pragma unroll
    for (int e = 0; e < 8; e++) {
      lA[fg * 8 + e][br] = (u16)va[e];
      lB[fg * 8 + e][br] = (u16)vb[e];
    }
    __syncthreads();
    int m = lane & 15, q = lane >> 4;
    bf16x8 a = *(const bf16x8*)&lA[16 * wid + m][8 * q];
#pragma unroll
    for (int tt = 0; tt < 4; tt++) {
      bf16x8 b = *(const bf16x8*)&lB[16 * tt + m][8 * q];
      acc[tt] = __builtin_amdgcn_mfma_f32_16x16x32_bf16(a, b, acc[tt], 0, 0, 0);
    }
    __syncthreads();
  }
  float* gp = Gpart + (((size_t)zi * 16 + chunk) * 36 + blockIdx.x) * 4096;
  int n = lane & 15, q = lane >> 4;
#pragma unroll
  for (int tt = 0; tt < 4; tt++)
#pragma unroll
    for (int r = 0; r < 4; r++)
      gp[(16 * wid + q * 4 + r) * 64 + 16 * tt + n] = acc[tt][r];
}

// ---------------- covariance off-diag reduce (triangle, weighted) ----------------
__global__ __launch_bounds__(256) void k_covreduce(const float* __restrict__ Gpart,
                                                   const float* __restrict__ csum,
                                                   float* __restrict__ scal) {
  int zi = blockIdx.y;
  int tile = blockIdx.x >> 4, part = blockIdx.x & 15;
  int ti = 0, xx = tile;
  while (xx >= 8 - ti) { xx -= 8 - ti; ti++; }
  int tj = ti + xx;
  int idx = part * 256 + threadIdx.x;
  int li = idx >> 6, lj = idx & 63;
  int i = ti * 64 + li, j = tj * 64 + lj;
  float g = 0.f;
#pragma unroll
  for (int c = 0; c < 16; c++)
    g += Gpart[(((size_t)zi * 16 + c) * 36 + tile) * 4096 + idx];
  float mi = csum[zi * D_N + i] * (1.0f / (float)B_N);
  float mj = csum[zi * D_N + j] * (1.0f / (float)B_N);
  float C = (g - (float)B_N * mi * mj) * (1.0f / (float)(B_N - 1));
  float wgt = (ti == tj) ? ((li == lj) ? 0.f : 1.f) : 2.f;
  float v = wgt * C * C;
  v = wred_sum(v);
  __shared__ float sw[4];
  if ((threadIdx.x & 63) == 0) sw[threadIdx.x >> 6] = v;
  __syncthreads();
  if (threadIdx.x == 0) atomicAdd(&scal[1], sw[0] + sw[1] + sw[2] + sw[3]);
}

// ---------------- logits = zn @ W^T, 128x128 tile, global_load_lds; fused rs0 ----------------
__global__ __launch_bounds__(256) void k_logits(const u16* __restrict__ zn1,
                                                const u16* __restrict__ zn2,
                                                const u16* __restrict__ Wb,
                                                u16* __restrict__ L1, u16* __restrict__ L2,
                                                float* __restrict__ rowsum) {
  int zi = blockIdx.z;
  const u16* A = zi ? zn2 : zn1;
  u16* Lout = zi ? L2 : L1;
  int b0 = blockIdx.x * 128, k0 = blockIdx.y * 128;
  __shared__ u16 lA[128 * 32], lB[128 * 32];
  int t = threadIdx.x, lane = t & 63, wid = t >> 6;
  int wm = wid >> 1, wn = wid & 1;
  f32x4 acc[4][4];
#pragma unroll
  for (int i = 0; i < 4; i++)
#pragma unroll
    for (int j = 0; j < 4; j++) acc[i][j] = (f32x4){0.f, 0.f, 0.f, 0.f};
  int row0 = t >> 2, seg0 = (t & 3) * 8;
  int ldsoff = (t & 192) * 16;  // wave-uniform byte offset
  for (int d0 = 0; d0 < D_N; d0 += 32) {
    gld16(A + (size_t)(b0 + row0) * D_N + d0 + seg0, (const u16*)((const char*)lA + ldsoff));
    gld16(A + (size_t)(b0 + 64 + row0) * D_N + d0 + seg0, (const u16*)((const char*)lA + 4096 + ldsoff));
    gld16(Wb + (size_t)(k0 + row0) * D_N + d0 + seg0, (const u16*)((const char*)lB + ldsoff));
    gld16(Wb + (size_t)(k0 + 64 + row0) * D_N + d0 + seg0, (const u16*)((const char*)lB + 4096 + ldsoff));
    __syncthreads();
    bf16x8 af[4], bfr[4];
#pragma unroll
    for (int i = 0; i < 4; i++)
      af[i] = *(const bf16x8*)&lA[(wm * 64 + i * 16 + (lane & 15)) * 32 + (lane >> 4) * 8];
#pragma unroll
    for (int j = 0; j < 4; j++)
      bfr[j] = *(const bf16x8*)&lB[(wn * 64 + j * 16 + (lane & 15)) * 32 + (lane >> 4) * 8];
#pragma unroll
    for (int i = 0; i < 4; i++)
#pragma unroll
      for (int j = 0; j < 4; j++)
        acc[i][j] = __builtin_amdgcn_mfma_f32_16x16x32_bf16(af[i], bfr[j], acc[i][j], 0, 0, 0);
    __syncthreads();
  }
  int cq = lane >> 4, cn = lane & 15;
  float rpart[4] = {0.f, 0.f, 0.f, 0.f};
#pragma unroll
  for (int i = 0; i < 4; i++)
#pragma unroll
    for (int j = 0; j < 4; j++)
#pragma unroll
      for (int r = 0; r < 4; r++) {
        u16 h = f2bf(acc[i][j][r]);
        int gb = b0 + wm * 64 + i * 16 + cq * 4 + r;
        int gk = k0 + wn * 64 + j * 16 + cn;
        Lout[(size_t)gb * K_N + gk] = h;
        rpart[j] += __expf(20.0f * bf2f((short)h));
      }
  float* red = (float*)lA;
  if (t < 128) red[t] = 0.f;
  __syncthreads();
#pragma unroll
  for (int j = 0; j < 4; j++) atomicAdd(&red[wn * 64 + j * 16 + cn], rpart[j]);
  __syncthreads();
  if (t < 128) atomicAdd(&rowsum[(size_t)zi * 3 * K_N + k0 + t], red[t]);
}

// ---------------- sinkhorn pass B: colsum_b = sum_k E*r (wave per row) ----------------
__global__ __launch_bounds__(256) void k_passB(const u16* __restrict__ L1,
                                               const u16* __restrict__ L2,
                                               const float* __restrict__ rowsum,
                                               float* __restrict__ colsum, int it) {
  int zi = blockIdx.y;
  const u16* L = zi ? L2 : L1;
  const float* rs = rowsum + ((size_t)zi * 3 + it) * K_N;
  float* cs = colsum + ((size_t)zi * 3 + it) * B_N;
  __shared__ float r[K_N];
  int t = threadIdx.x, lane = t & 63, wid = t >> 6;
  for (int k = t; k < K_N; k += 256) r[k] = 1.0f / ((float)K_N * rs[k]);
  __syncthreads();
  int w = blockIdx.x * 4 + wid;
  for (int rr = 0; rr < 32; rr++) {
    int b = w * 32 + rr;
    float a = 0.f;
#pragma unroll
    for (int jj = 0; jj < 4; jj++) {
      bf16x8 v = *(const bf16x8*)&L[(size_t)b * K_N + jj * 512 + lane * 8];
#pragma unroll
      for (int e = 0; e < 8; e++)
        a += __expf(20.0f * bf2f(v[e])) * r[jj * 512 + lane * 8 + e];
    }
    a = wred_sum(a);
    if (lane == 0) cs[b] = a;
  }
}

// ---------------- sinkhorn pass A: rowsum_k = sum_b E*c ----------------
__global__ __launch_bounds__(256) void k_passA(const u16* __restrict__ L1,
                                               const u16* __restrict__ L2,
                                               const float* __restrict__ colsum,
                                               float* __restrict__ rowsum, int it) {
  int zi = blockIdx.y;
  const u16* L = zi ? L2 : L1;
  const float* cs = colsum + ((size_t)zi * 3 + (it - 1)) * B_N;
  float* rs = rowsum + ((size_t)zi * 3 + it) * K_N;
  int t = threadIdx.x;
  int k8 = t * 8;
  float racc[8];
#pragma unroll
  for (int e = 0; e < 8; e++) racc[e] = 0.f;
  for (int rr = 0; rr < 64; rr++) {
    int b = blockIdx.x * 64 + rr;
    float cb = 1.0f / ((float)B_N * cs[b]);
    bf16x8 v = *(const bf16x8*)&L[(size_t)b * K_N + k8];
#pragma unroll
    for (int e = 0; e < 8; e++) racc[e] += __expf(20.0f * bf2f(v[e])) * cb;
  }
#pragma unroll
  for (int e = 0; e < 8; e++) atomicAdd(&rs[k8 + e], racc[e]);
}

// ---------------- final fused pass: CE + diagnostics, wave-parallel ----------------
__global__ __launch_bounds__(256) void k_final(const u16* __restrict__ L1,
                                               const u16* __restrict__ L2,
                                               const float* __restrict__ rowsum,
                                               float* __restrict__ probsum,
                                               int* __restrict__ counts,
                                               float* __restrict__ scal) {
  __shared__ float r1s[K_N], lr1s[K_N], r2s[K_N], lr2s[K_N], pmerge[K_N];
  __shared__ int cnt[K_N];
  const float* rs1 = rowsum + 2 * K_N;
  const float* rs2 = rowsum + 5 * K_N;
  int t = threadIdx.x, lane = t & 63, wid = t >> 6;
  for (int k = t; k < K_N; k += 256) {
    float a = 1.0f / ((float)K_N * rs1[k]); r1s[k] = a; lr1s[k] = __logf(a);
    float b = 1.0f / ((float)K_N * rs2[k]); r2s[k] = b; lr2s[k] = __logf(b);
    pmerge[k] = 0.f; cnt[k] = 0;
  }
  __syncthreads();
  float pacc[32];
#pragma unroll
  for (int q = 0; q < 32; q++) pacc[q] = 0.f;
  float ce_acc = 0.f; int acc_cnt = 0;
  int w = blockIdx.x * 4 + wid;  // 0..1023 (grid 256)
  for (int rr = 0; rr < 16; rr++) {
    int b = w * 16 + rr;  // 0..16383
    bf16x8 v1[4], v2[4];
#pragma unroll
    for (int jj = 0; jj < 4; jj++) {
      v1[jj] = *(const bf16x8*)&L1[(size_t)b * K_N + jj * 512 + lane * 8];
      v2[jj] = *(const bf16x8*)&L2[(size_t)b * K_N + jj * 512 + lane * 8];
    }
    float sE1 = 0, sE2 = 0, d12 = 0, d21 = 0, Z1 = 0, Z2 = 0;
    float m1v = -1e30f, m2v = -1e30f, a1v = -1e30f, a2v = -1e30f;
    int m1i = 0, m2i = 0, a1i = 0, a2i = 0;
#pragma unroll
    for (int jj = 0; jj < 4; jj++)
#pragma unroll
      for (int e = 0; e < 8; e++) {
        int k = jj * 512 + lane * 8 + e;
        float x1 = bf2f(v1[jj][e]), x2 = bf2f(v2[jj][e]);
        float t1 = __expf(10.0f * x1), t2 = __expf(10.0f * x2);
        float e1 = t1 * t1 * r1s[k], e2 = t2 * t2 * r2s[k];
        sE1 += e1; sE2 += e2;
        d12 += e1 * x2; d21 += e2 * x1;
        Z1 += t1; Z2 += t2;
        if (x1 > m1v) { m1v = x1; m1i = k; }
        if (x2 > m2v) { m2v = x2; m2i = k; }
        float s1 = 20.0f * x1 + lr1s[k];
        if (s1 > a1v) { a1v = s1; a1i = k; }
        float s2 = 20.0f * x2 + lr2s[k];
        if (s2 > a2v) { a2v = s2; a2i = k; }
      }
#pragma unroll
    for (int o = 32; o; o >>= 1) {
      sE1 += __shfl_xor(sE1, o, 64);
      sE2 += __shfl_xor(sE2, o, 64);
      d12 += __shfl_xor(d12, o, 64);
      d21 += __shfl_xor(d21, o, 64);
      Z1 += __shfl_xor(Z1, o, 64);
      Z2 += __shfl_xor(Z2, o, 64);
      float ov; int oi;
      ov = __shfl_xor(m1v, o, 64); oi = __shfl_xor(m1i, o, 64);
      if (ov > m1v || (ov == m1v && oi < m1i)) { m1v = ov; m1i = oi; }
      ov = __shfl_xor(m2v, o, 64); oi = __shfl_xor(m2i, o, 64);
      if (ov > m2v || (ov == m2v && oi < m2i)) { m2v = ov; m2i = oi; }
      ov = __shfl_xor(a1v, o, 64); oi = __shfl_xor(a1i, o, 64);
      if (ov > a1v || (ov == a1v && oi < a1i)) { a1v = ov; a1i = oi; }
      ov = __shfl_xor(a2v, o, 64); oi = __shfl_xor(a2i, o, 64);
      if (ov > a2v || (ov == a2v && oi < a2i)) { a2v = ov; a2i = oi; }
    }
    // cs2 (final sinkhorn colsum) == sE (computed in-place; pass B it=2 eliminated)
    float invc1 = 1.0f / sE1, invc2 = 1.0f / sE2;
    float lZ1 = __logf(Z1), lZ2 = __logf(Z2);
    ce_acc += (10.0f * d12) * invc1 - lZ2 + (10.0f * d21) * invc2 - lZ1;
    acc_cnt += (m1i == a2i) + (m2i == a1i);
    if (lane == 0) { atomicAdd(&cnt[m1i], 1); atomicAdd(&cnt[m2i], 1); }
    float iZ1 = 1.0f / Z1, iZ2 = 1.0f / Z2;
#pragma unroll
    for (int jj = 0; jj < 4; jj++)
#pragma unroll
      for (int e = 0; e < 8; e++) {
        float x1 = bf2f(v1[jj][e]), x2 = bf2f(v2[jj][e]);
        pacc[jj * 8 + e] += __expf(10.0f * x1) * iZ1 + __expf(10.0f * x2) * iZ2;
      }
  }
  if (lane == 0) {
    atomicAdd(&scal[2], ce_acc);
    atomicAdd(&scal[3], (float)acc_cnt);
  }
#pragma unroll
  for (int q = 0; q < 32; q++) {
    int k = (q >> 3) * 512 + lane * 8 + (q & 7);
    atomicAdd(&pmerge[k], pacc[q]);
  }
  __syncthreads();
  for (int k = t; k < K_N; k += 256) {
    atomicAdd(&probsum[k], pmerge[k]);
    atomicAdd(&counts[k], cnt[k]);
  }
}

// ---------------- combine: all 7 outputs ----------------
__global__ __launch_bounds__(256) void k_combine(const float* __restrict__ scal,
                                                 const float* __restrict__ probsum,
                                                 const int* __restrict__ counts,
                                                 float* __restrict__ out) {
  int t = threadIdx.x;
  float ec = 0.f, ep = 0.f;
  for (int k = t; k < K_N; k += 256) {
    float p = (float)counts[k] * (1.0f / (2.0f * (float)B_N));
    ec += -p * __logf(p + 1e-7f);
    float q = probsum[k] * (1.0f / (2.0f * (float)B_N));
    ep += -q * __logf(q + 1e-7f);
  }
  ec = wred_sum(ec);
  ep = wred_sum(ep);
  __shared__ float se[4], sp[4];
  if ((t & 63) == 0) { se[t >> 6] = ec; sp[t >> 6] = ep; }
  __syncthreads();
  if (t == 0) {
    float tec = se[0] + se[1] + se[2] + se[3];
    float tep = sp[0] + sp[1] + sp[2] + sp[3];
    float ce = -0.5f * scal[2] * (1.0f / (float)B_N);
    float lvar = scal[0] * (1.0f / (float)D_N);
    float lcov = scal[1] * (1.0f / (float)D_N);
    float acc = scal[3] * (1.0f / (2.0f * (float)B_N));
    out[0] = 15.0f * ce + lvar + lcov;
    out[1] = ce;
    out[2] = lvar;
    out[3] = lcov;
    out[4] = __expf(tec);
    out[5] = __expf(tep);
    out[6] = acc;
  }
}

extern "C" void kernel_launch(void* const* d_in, const int* in_sizes, int n_in,
                              void* d_out, int out_size, void* d_ws, size_t ws_size,
                              hipStream_t stream) {
  (void)in_sizes; (void)n_in; (void)out_size; (void)ws_size;
  const float* z1 = (const float*)d_in[0];
  const float* z2 = (const float*)d_in[1];
  const float* W = (const float*)d_in[2];

  char* w = (char*)d_ws;
  size_t off = 0;
  auto take = [&](size_t b) -> void* {
    void* p = w + off;
    off = (off + b + 255) & ~(size_t)255;
    return p;
  };
  float* rowsum = (float*)take(2 * 3 * K_N * 4);
  float* csum = (float*)take(2 * D_N * 4);
  float* csumsq = (float*)take(2 * D_N * 4);
  float* probsum = (float*)take(K_N * 4);
  int* counts = (int*)take(K_N * 4);
  float* scal = (float*)take(64);
  size_t zero_bytes = off;
  float* colsum = (float*)take((size_t)2 * 3 * B_N * 4);
  u16* zn1 = (u16*)take((size_t)B_N * D_N * 2);
  u16* zn2 = (u16*)take((size_t)B_N * D_N * 2);
  u16* Wb = (u16*)take((size_t)K_N * D_N * 2);
  u16* L1 = (u16*)take((size_t)B_N * K_N * 2);
  u16* L2 = (u16*)take((size_t)B_N * K_N * 2);
  float* Gpart = (float*)take((size_t)2 * 16 * 36 * 4096 * 4);
  // raw-bf16 z aliases the (not yet live) L1 buffer; gram/colstats finish before k_logits
  u16* zb1 = L1;
  u16* zb2 = L1 + (size_t)B_N * D_N;

  hipMemsetAsync(d_ws, 0, zero_bytes, stream);

  k_rownorm<<<8192, 256, 0, stream>>>(z1, z2, zn1, zn2, zb1, zb2);
  k_convW<<<512, 256, 0, stream>>>(W, Wb);
  k_colstats<<<dim3(1, 64, 2), dim3(64, 8), 0, stream>>>(zb1, zb2, csum, csumsq);
  k_vloss<<<4, 256, 0, stream>>>(csum, csumsq, scal);
  k_gram<<<dim3(36, 1, 32), 256, 0, stream>>>(zb1, zb2, Gpart);
  k_covreduce<<<dim3(36 * 16, 2), 256, 0, stream>>>(Gpart, csum, scal);
  k_logits<<<dim3(128, 16, 2), 256, 0, stream>>>(zn1, zn2, Wb, L1, L2, rowsum);
  k_passB<<<dim3(128, 2), 256, 0, stream>>>(L1, L2, rowsum, colsum, 0);
  k_passA<<<dim3(256, 2), 256, 0, stream>>>(L1, L2, colsum, rowsum, 1);
  k_passB<<<dim3(128, 2), 256, 0, stream>>>(L1, L2, rowsum, colsum, 1);
  k_passA<<<dim3(256, 2), 256, 0, stream>>>(L1, L2, colsum, rowsum, 2);
  k_final<<<256, 256, 0, stream>>>(L1, L2, rowsum, probsum, counts, scal);
  k_combine<<<1, 256, 0, stream>>>(scal, probsum, counts, (float*)d_out);
}

// Round 4
// 591.941 us; speedup vs baseline: 1.6851x; 1.2172x over previous
//
#include <hip/hip_runtime.h>
#include <hip/hip_bf16.h>

#define B_N 16384
#define D_N 512
#define K_N 2048

typedef __attribute__((ext_vector_type(8))) short bf16x8;
typedef __attribute__((ext_vector_type(4))) float f32x4;
typedef __attribute__((ext_vector_type(4))) unsigned short u16x4;
typedef unsigned short u16;

__device__ __forceinline__ float bf2f(short s) {
  return __builtin_bit_cast(float, ((unsigned)(u16)s) << 16);
}
__device__ __forceinline__ u16 f2bf(float x) {
  return __builtin_bit_cast(u16, __float2bfloat16(x));
}
__device__ __forceinline__ float wred_sum(float v) {
#pragma unroll
  for (int o = 32; o; o >>= 1) v += __shfl_down(v, o, 64);
  return v;
}

__device__ __forceinline__ void gld16(const u16* g, const u16* l) {
  __builtin_amdgcn_global_load_lds((const __attribute__((address_space(1))) void*)g,
                                   (__attribute__((address_space(3))) void*)l, 16, 0, 0);
}

// ---------------- row l2norm + bf16 convert (normalized + raw) ----------------
__global__ __launch_bounds__(256) void k_rownorm(const float* __restrict__ z1,
                                                 const float* __restrict__ z2,
                                                 u16* __restrict__ zn1, u16* __restrict__ zn2,
                                                 u16* __restrict__ zb1, u16* __restrict__ zb2) {
  int wid = threadIdx.x >> 6, lane = threadIdx.x & 63;
  int row = blockIdx.x * 4 + wid;
  const float* z; u16 *zn, *zb; int r;
  if (row < B_N) { z = z1; zn = zn1; zb = zb1; r = row; }
  else { z = z2; zn = zn2; zb = zb2; r = row - B_N; }
  const float4* zr = (const float4*)(z + (size_t)r * D_N);
  float4 va = zr[lane], vb = zr[lane + 64];
  float ss = va.x*va.x + va.y*va.y + va.z*va.z + va.w*va.w
           + vb.x*vb.x + vb.y*vb.y + vb.z*vb.z + vb.w*vb.w;
#pragma unroll
  for (int o = 32; o; o >>= 1) ss += __shfl_xor(ss, o, 64);
  float inv = 1.0f / fmaxf(sqrtf(ss), 1e-12f);
  u16x4 pa = {f2bf(va.x), f2bf(va.y), f2bf(va.z), f2bf(va.w)};
  u16x4 pb = {f2bf(vb.x), f2bf(vb.y), f2bf(vb.z), f2bf(vb.w)};
  u16x4 na = {f2bf(va.x*inv), f2bf(va.y*inv), f2bf(va.z*inv), f2bf(va.w*inv)};
  u16x4 nb = {f2bf(vb.x*inv), f2bf(vb.y*inv), f2bf(vb.z*inv), f2bf(vb.w*inv)};
  ((u16x4*)(zb + (size_t)r * D_N))[lane] = pa;
  ((u16x4*)(zb + (size_t)r * D_N))[lane + 64] = pb;
  ((u16x4*)(zn + (size_t)r * D_N))[lane] = na;
  ((u16x4*)(zn + (size_t)r * D_N))[lane + 64] = nb;
}

// ---------------- W -> bf16 ----------------
__global__ __launch_bounds__(256) void k_convW(const float* __restrict__ W,
                                               u16* __restrict__ Wb) {
  size_t base = ((size_t)blockIdx.x * 256 + threadIdx.x) * 8;
#pragma unroll
  for (int j = 0; j < 8; j++) Wb[base + j] = f2bf(W[base + j]);
}

// ---------------- per-column sum / sumsq (bf16 input) ----------------
__global__ __launch_bounds__(512) void k_colstats(const u16* __restrict__ zb1,
                                                  const u16* __restrict__ zb2,
                                                  float* __restrict__ csum,
                                                  float* __restrict__ csumsq) {
  int zi = blockIdx.z;
  const u16* z = zi ? zb2 : zb1;
  __shared__ float s1[512], s2[512];
  int t = threadIdx.y * 64 + threadIdx.x;
  s1[t] = 0.f; s2[t] = 0.f;
  __syncthreads();
  int c0 = threadIdx.x * 8;
  float a[8], a2[8];
#pragma unroll
  for (int e = 0; e < 8; e++) { a[e] = 0.f; a2[e] = 0.f; }
  for (int u = 0; u < 16; u++) {
    int r = blockIdx.y * 128 + threadIdx.y + 8 * u;
    bf16x8 v = *(const bf16x8*)&z[(size_t)r * D_N + c0];
#pragma unroll
    for (int e = 0; e < 8; e++) { float x = bf2f(v[e]); a[e] += x; a2[e] += x * x; }
  }
#pragma unroll
  for (int e = 0; e < 8; e++) {
    atomicAdd(&s1[c0 + e], a[e]);
    atomicAdd(&s2[c0 + e], a2[e]);
  }
  __syncthreads();
  atomicAdd(&csum[zi * D_N + t], s1[t]);
  atomicAdd(&csumsq[zi * D_N + t], s2[t]);
}

// ---------------- variance hinge loss ----------------
__global__ __launch_bounds__(256) void k_vloss(const float* __restrict__ csum,
                                               const float* __restrict__ csumsq,
                                               float* __restrict__ scal) {
  int idx = blockIdx.x * 256 + threadIdx.x;  // < 1024
  float s = csum[idx], sq = csumsq[idx];
  float mean = s * (1.0f / (float)B_N);
  float var = (sq - (float)B_N * mean * mean) * (1.0f / (float)(B_N - 1));
  float term = fmaxf(0.f, 0.2f - sqrtf(var + 1e-8f));
  term = wred_sum(term);
  __shared__ float sw[4];
  if ((threadIdx.x & 63) == 0) sw[threadIdx.x >> 6] = term;
  __syncthreads();
  if (threadIdx.x == 0) atomicAdd(&scal[0], sw[0] + sw[1] + sw[2] + sw[3]);
}

// ---------------- gram (bf16 input, upper-triangle tiles, split-K 16) ----------------
__global__ __launch_bounds__(256) void k_gram(const u16* __restrict__ zb1,
                                              const u16* __restrict__ zb2,
                                              float* __restrict__ Gpart) {
  int zi = blockIdx.z >> 4, chunk = blockIdx.z & 15;
  const u16* z = zi ? zb2 : zb1;
  int ti = 0, xx = blockIdx.x;
  while (xx >= 8 - ti) { xx -= 8 - ti; ti++; }
  int tj = ti + xx;
  int i0 = ti * 64, j0 = tj * 64;
  __shared__ u16 lA[64][32], lB[64][32];
  int t = threadIdx.x, wid = t >> 6, lane = t & 63;
  int br = t & 31, fg = t >> 5;
  f32x4 acc[4];
#pragma unroll
  for (int q = 0; q < 4; q++) acc[q] = (f32x4){0.f, 0.f, 0.f, 0.f};
  for (int bb = 0; bb < 1024; bb += 32) {
    size_t rb = ((size_t)chunk * 1024 + bb + br) * D_N;
    bf16x8 va = *(const bf16x8*)&z[rb + i0 + fg * 8];
    bf16x8 vb = *(const bf16x8*)&z[rb + j0 + fg * 8];
#pragma unroll
    for (int e = 0; e < 8; e++) {
      lA[fg * 8 + e][br] = (u16)va[e];
      lB[fg * 8 + e][br] = (u16)vb[e];
    }
    __syncthreads();
    int m = lane & 15, q = lane >> 4;
    bf16x8 a = *(const bf16x8*)&lA[16 * wid + m][8 * q];
#pragma unroll
    for (int tt = 0; tt < 4; tt++) {
      bf16x8 b = *(const bf16x8*)&lB[16 * tt + m][8 * q];
      acc[tt] = __builtin_amdgcn_mfma_f32_16x16x32_bf16(a, b, acc[tt], 0, 0, 0);
    }
    __syncthreads();
  }
  float* gp = Gpart + (((size_t)zi * 16 + chunk) * 36 + blockIdx.x) * 4096;
  int n = lane & 15, q = lane >> 4;
#pragma unroll
  for (int tt = 0; tt < 4; tt++)
#pragma unroll
    for (int r = 0; r < 4; r++)
      gp[(16 * wid + q * 4 + r) * 64 + 16 * tt + n] = acc[tt][r];
}

// ---------------- covariance off-diag reduce (triangle, weighted) ----------------
__global__ __launch_bounds__(256) void k_covreduce(const float* __restrict__ Gpart,
                                                   const float* __restrict__ csum,
                                                   float* __restrict__ scal) {
  int zi = blockIdx.y;
  int tile = blockIdx.x >> 4, part = blockIdx.x & 15;
  int ti = 0, xx = tile;
  while (xx >= 8 - ti) { xx -= 8 - ti; ti++; }
  int tj = ti + xx;
  int idx = part * 256 + threadIdx.x;
  int li = idx >> 6, lj = idx & 63;
  int i = ti * 64 + li, j = tj * 64 + lj;
  float g = 0.f;
#pragma unroll
  for (int c = 0; c < 16; c++)
    g += Gpart[(((size_t)zi * 16 + c) * 36 + tile) * 4096 + idx];
  float mi = csum[zi * D_N + i] * (1.0f / (float)B_N);
  float mj = csum[zi * D_N + j] * (1.0f / (float)B_N);
  float C = (g - (float)B_N * mi * mj) * (1.0f / (float)(B_N - 1));
  float wgt = (ti == tj) ? ((li == lj) ? 0.f : 1.f) : 2.f;
  float v = wgt * C * C;
  v = wred_sum(v);
  __shared__ float sw[4];
  if ((threadIdx.x & 63) == 0) sw[threadIdx.x >> 6] = v;
  __syncthreads();
  if (threadIdx.x == 0) atomicAdd(&scal[1], sw[0] + sw[1] + sw[2] + sw[3]);
}

// ---------------- logits = zn @ W^T, 128x128 tile, global_load_lds; fused rs0 ----------------
__global__ __launch_bounds__(256) void k_logits(const u16* __restrict__ zn1,
                                                const u16* __restrict__ zn2,
                                                const u16* __restrict__ Wb,
                                                u16* __restrict__ L1, u16* __restrict__ L2,
                                                float* __restrict__ rowsum) {
  int zi = blockIdx.z;
  const u16* A = zi ? zn2 : zn1;
  u16* Lout = zi ? L2 : L1;
  int b0 = blockIdx.x * 128, k0 = blockIdx.y * 128;
  __shared__ u16 lA[128 * 32], lB[128 * 32];
  int t = threadIdx.x, lane = t & 63, wid = t >> 6;
  int wm = wid >> 1, wn = wid & 1;
  f32x4 acc[4][4];
#pragma unroll
  for (int i = 0; i < 4; i++)
#pragma unroll
    for (int j = 0; j < 4; j++) acc[i][j] = (f32x4){0.f, 0.f, 0.f, 0.f};
  int row0 = t >> 2, seg0 = (t & 3) * 8;
  int ldsoff = (t & 192) * 16;  // wave-uniform byte offset
  for (int d0 = 0; d0 < D_N; d0 += 32) {
    gld16(A + (size_t)(b0 + row0) * D_N + d0 + seg0, (const u16*)((const char*)lA + ldsoff));
    gld16(A + (size_t)(b0 + 64 + row0) * D_N + d0 + seg0, (const u16*)((const char*)lA + 4096 + ldsoff));
    gld16(Wb + (size_t)(k0 + row0) * D_N + d0 + seg0, (const u16*)((const char*)lB + ldsoff));
    gld16(Wb + (size_t)(k0 + 64 + row0) * D_N + d0 + seg0, (const u16*)((const char*)lB + 4096 + ldsoff));
    __syncthreads();
    bf16x8 af[4], bfr[4];
#pragma unroll
    for (int i = 0; i < 4; i++)
      af[i] = *(const bf16x8*)&lA[(wm * 64 + i * 16 + (lane & 15)) * 32 + (lane >> 4) * 8];
#pragma unroll
    for (int j = 0; j < 4; j++)
      bfr[j] = *(const bf16x8*)&lB[(wn * 64 + j * 16 + (lane & 15)) * 32 + (lane >> 4) * 8];
#pragma unroll
    for (int i = 0; i < 4; i++)
#pragma unroll
      for (int j = 0; j < 4; j++)
        acc[i][j] = __builtin_amdgcn_mfma_f32_16x16x32_bf16(af[i], bfr[j], acc[i][j], 0, 0, 0);
    __syncthreads();
  }
  int cq = lane >> 4, cn = lane & 15;
  float rpart[4] = {0.f, 0.f, 0.f, 0.f};
#pragma unroll
  for (int i = 0; i < 4; i++)
#pragma unroll
    for (int j = 0; j < 4; j++)
#pragma unroll
      for (int r = 0; r < 4; r++) {
        u16 h = f2bf(acc[i][j][r]);
        int gb = b0 + wm * 64 + i * 16 + cq * 4 + r;
        int gk = k0 + wn * 64 + j * 16 + cn;
        Lout[(size_t)gb * K_N + gk] = h;
        rpart[j] += __expf(20.0f * bf2f((short)h));
      }
  float* red = (float*)lA;
  if (t < 128) red[t] = 0.f;
  __syncthreads();
#pragma unroll
  for (int j = 0; j < 4; j++) atomicAdd(&red[wn * 64 + j * 16 + cn], rpart[j]);
  __syncthreads();
  if (t < 128) atomicAdd(&rowsum[(size_t)zi * 3 * K_N + k0 + t], red[t]);
}

// ---------------- fused sinkhorn half-iteration pair:
// c_it[b] = sum_k E[b,k]*r_it[k]  (in-wave), then rs_{it+1}[k] += E[b,k]/(B*c_it[b])
__global__ __launch_bounds__(256) void k_sink(const u16* __restrict__ L1,
                                              const u16* __restrict__ L2,
                                              float* __restrict__ rowsum, int it) {
  int zi = blockIdx.y;
  const u16* L = zi ? L2 : L1;
  const float* rs_in = rowsum + ((size_t)zi * 3 + it) * K_N;
  float* rs_out = rowsum + ((size_t)zi * 3 + it + 1) * K_N;
  __shared__ float pm[K_N];
  int t = threadIdx.x, lane = t & 63, wid = t >> 6;
  for (int k = t; k < K_N; k += 256) pm[k] = 0.f;
  // per-lane r values: fixed 32-k set across all rows -> registers
  float rv[32];
#pragma unroll
  for (int jj = 0; jj < 4; jj++) {
    const float4* p = (const float4*)&rs_in[jj * 512 + lane * 8];
    float4 x = p[0], y = p[1];
    rv[jj*8+0] = 1.0f / ((float)K_N * x.x); rv[jj*8+1] = 1.0f / ((float)K_N * x.y);
    rv[jj*8+2] = 1.0f / ((float)K_N * x.z); rv[jj*8+3] = 1.0f / ((float)K_N * x.w);
    rv[jj*8+4] = 1.0f / ((float)K_N * y.x); rv[jj*8+5] = 1.0f / ((float)K_N * y.y);
    rv[jj*8+6] = 1.0f / ((float)K_N * y.z); rv[jj*8+7] = 1.0f / ((float)K_N * y.w);
  }
  __syncthreads();
  float racc[32];
#pragma unroll
  for (int q = 0; q < 32; q++) racc[q] = 0.f;
  int w = blockIdx.x * 4 + wid;  // 0..2047
  for (int rr = 0; rr < 8; rr++) {
    int b = w * 8 + rr;
    float ex[32];
    float c = 0.f;
#pragma unroll
    for (int jj = 0; jj < 4; jj++) {
      bf16x8 v = *(const bf16x8*)&L[(size_t)b * K_N + jj * 512 + lane * 8];
#pragma unroll
      for (int e = 0; e < 8; e++) {
        float E = __expf(20.0f * bf2f(v[e]));
        ex[jj * 8 + e] = E;
        c += E * rv[jj * 8 + e];
      }
    }
#pragma unroll
    for (int o = 32; o; o >>= 1) c += __shfl_xor(c, o, 64);
    float cb = 1.0f / ((float)B_N * c);
#pragma unroll
    for (int q = 0; q < 32; q++) racc[q] += ex[q] * cb;
  }
#pragma unroll
  for (int q = 0; q < 32; q++)
    atomicAdd(&pm[(q >> 3) * 512 + lane * 8 + (q & 7)], racc[q]);
  __syncthreads();
  for (int k = t; k < K_N; k += 256) atomicAdd(&rs_out[k], pm[k]);
}

// ---------------- final fused pass: CE + diagnostics, wave-parallel ----------------
__global__ __launch_bounds__(256) void k_final(const u16* __restrict__ L1,
                                               const u16* __restrict__ L2,
                                               const float* __restrict__ rowsum,
                                               float* __restrict__ probsum,
                                               int* __restrict__ counts,
                                               float* __restrict__ scal) {
  __shared__ float r1s[K_N], r2s[K_N], pmerge[K_N];
  const float* rs1 = rowsum + 2 * K_N;
  const float* rs2 = rowsum + 5 * K_N;
  int t = threadIdx.x, lane = t & 63, wid = t >> 6;
  for (int k = t; k < K_N; k += 256) {
    r1s[k] = 1.0f / ((float)K_N * rs1[k]);
    r2s[k] = 1.0f / ((float)K_N * rs2[k]);
    pmerge[k] = 0.f;
  }
  __syncthreads();
  float pacc[32];
#pragma unroll
  for (int q = 0; q < 32; q++) pacc[q] = 0.f;
  float ce_acc = 0.f; int acc_cnt = 0;
  int w = blockIdx.x * 4 + wid;  // 0..4095
  for (int rr = 0; rr < 4; rr++) {
    int b = w * 4 + rr;  // 0..16383
    float t1v[32], t2v[32];
    float sE1 = 0, sE2 = 0, d12 = 0, d21 = 0, Z1 = 0, Z2 = 0;
    float m1v = -1e30f, m2v = -1e30f, a1v = -1e30f, a2v = -1e30f;
    int m1i = 0, m2i = 0, a1i = 0, a2i = 0;
#pragma unroll
    for (int jj = 0; jj < 4; jj++) {
      bf16x8 v1 = *(const bf16x8*)&L1[(size_t)b * K_N + jj * 512 + lane * 8];
      bf16x8 v2 = *(const bf16x8*)&L2[(size_t)b * K_N + jj * 512 + lane * 8];
#pragma unroll
      for (int e = 0; e < 8; e++) {
        int k = jj * 512 + lane * 8 + e;
        float x1 = bf2f(v1[e]), x2 = bf2f(v2[e]);
        float t1 = __expf(10.0f * x1), t2 = __expf(10.0f * x2);
        t1v[jj * 8 + e] = t1; t2v[jj * 8 + e] = t2;
        float e1 = t1 * t1 * r1s[k], e2 = t2 * t2 * r2s[k];
        sE1 += e1; sE2 += e2;
        d12 += e1 * x2; d21 += e2 * x1;
        Z1 += t1; Z2 += t2;
        if (x1 > m1v) { m1v = x1; m1i = k; }
        if (x2 > m2v) { m2v = x2; m2i = k; }
        // argmax(20x + log r) == argmax(exp(20x)*r) == argmax e
        if (e1 > a1v) { a1v = e1; a1i = k; }
        if (e2 > a2v) { a2v = e2; a2i = k; }
      }
    }
#pragma unroll
    for (int o = 32; o; o >>= 1) {
      sE1 += __shfl_xor(sE1, o, 64);
      sE2 += __shfl_xor(sE2, o, 64);
      d12 += __shfl_xor(d12, o, 64);
      d21 += __shfl_xor(d21, o, 64);
      Z1 += __shfl_xor(Z1, o, 64);
      Z2 += __shfl_xor(Z2, o, 64);
      float ov; int oi;
      ov = __shfl_xor(m1v, o, 64); oi = __shfl_xor(m1i, o, 64);
      if (ov > m1v || (ov == m1v && oi < m1i)) { m1v = ov; m1i = oi; }
      ov = __shfl_xor(m2v, o, 64); oi = __shfl_xor(m2i, o, 64);
      if (ov > m2v || (ov == m2v && oi < m2i)) { m2v = ov; m2i = oi; }
      ov = __shfl_xor(a1v, o, 64); oi = __shfl_xor(a1i, o, 64);
      if (ov > a1v || (ov == a1v && oi < a1i)) { a1v = ov; a1i = oi; }
      ov = __shfl_xor(a2v, o, 64); oi = __shfl_xor(a2i, o, 64);
      if (ov > a2v || (ov == a2v && oi < a2i)) { a2v = ov; a2i = oi; }
    }
    // cs2 (final sinkhorn colsum) == sE (pass B it=2 eliminated)
    float invc1 = 1.0f / sE1, invc2 = 1.0f / sE2;
    float lZ1 = __logf(Z1), lZ2 = __logf(Z2);
    ce_acc += (10.0f * d12) * invc1 - lZ2 + (10.0f * d21) * invc2 - lZ1;
    acc_cnt += (m1i == a2i) + (m2i == a1i);
    if (lane == 0) { atomicAdd(&counts[m1i], 1); atomicAdd(&counts[m2i], 1); }
    float iZ1 = 1.0f / Z1, iZ2 = 1.0f / Z2;
#pragma unroll
    for (int q = 0; q < 32; q++)
      pacc[q] += t1v[q] * iZ1 + t2v[q] * iZ2;
  }
  if (lane == 0) {
    atomicAdd(&scal[2], ce_acc);
    atomicAdd(&scal[3], (float)acc_cnt);
  }
#pragma unroll
  for (int q = 0; q < 32; q++) {
    int k = (q >> 3) * 512 + lane * 8 + (q & 7);
    atomicAdd(&pmerge[k], pacc[q]);
  }
  __syncthreads();
  for (int k = t; k < K_N; k += 256) atomicAdd(&probsum[k], pmerge[k]);
}

// ---------------- combine: all 7 outputs ----------------
__global__ __launch_bounds__(256) void k_combine(const float* __restrict__ scal,
                                                 const float* __restrict__ probsum,
                                                 const int* __restrict__ counts,
                                                 float* __restrict__ out) {
  int t = threadIdx.x;
  float ec = 0.f, ep = 0.f;
  for (int k = t; k < K_N; k += 256) {
    float p = (float)counts[k] * (1.0f / (2.0f * (float)B_N));
    ec += -p * __logf(p + 1e-7f);
    float q = probsum[k] * (1.0f / (2.0f * (float)B_N));
    ep += -q * __logf(q + 1e-7f);
  }
  ec = wred_sum(ec);
  ep = wred_sum(ep);
  __shared__ float se[4], sp[4];
  if ((t & 63) == 0) { se[t >> 6] = ec; sp[t >> 6] = ep; }
  __syncthreads();
  if (t == 0) {
    float tec = se[0] + se[1] + se[2] + se[3];
    float tep = sp[0] + sp[1] + sp[2] + sp[3];
    float ce = -0.5f * scal[2] * (1.0f / (float)B_N);
    float lvar = scal[0] * (1.0f / (float)D_N);
    float lcov = scal[1] * (1.0f / (float)D_N);
    float acc = scal[3] * (1.0f / (2.0f * (float)B_N));
    out[0] = 15.0f * ce + lvar + lcov;
    out[1] = ce;
    out[2] = lvar;
    out[3] = lcov;
    out[4] = __expf(tec);
    out[5] = __expf(tep);
    out[6] = acc;
  }
}

extern "C" void kernel_launch(void* const* d_in, const int* in_sizes, int n_in,
                              void* d_out, int out_size, void* d_ws, size_t ws_size,
                              hipStream_t stream) {
  (void)in_sizes; (void)n_in; (void)out_size; (void)ws_size;
  const float* z1 = (const float*)d_in[0];
  const float* z2 = (const float*)d_in[1];
  const float* W = (const float*)d_in[2];

  char* w = (char*)d_ws;
  size_t off = 0;
  auto take = [&](size_t b) -> void* {
    void* p = w + off;
    off = (off + b + 255) & ~(size_t)255;
    return p;
  };
  float* rowsum = (float*)take(2 * 3 * K_N * 4);
  float* csum = (float*)take(2 * D_N * 4);
  float* csumsq = (float*)take(2 * D_N * 4);
  float* probsum = (float*)take(K_N * 4);
  int* counts = (int*)take(K_N * 4);
  float* scal = (float*)take(64);
  size_t zero_bytes = off;
  u16* zn1 = (u16*)take((size_t)B_N * D_N * 2);
  u16* zn2 = (u16*)take((size_t)B_N * D_N * 2);
  u16* Wb = (u16*)take((size_t)K_N * D_N * 2);
  u16* L1 = (u16*)take((size_t)B_N * K_N * 2);
  u16* L2 = (u16*)take((size_t)B_N * K_N * 2);
  float* Gpart = (float*)take((size_t)2 * 16 * 36 * 4096 * 4);
  // raw-bf16 z aliases the (not yet live) L1 buffer; gram/colstats finish before k_logits
  u16* zb1 = L1;
  u16* zb2 = L1 + (size_t)B_N * D_N;

  hipMemsetAsync(d_ws, 0, zero_bytes, stream);

  k_rownorm<<<8192, 256, 0, stream>>>(z1, z2, zn1, zn2, zb1, zb2);
  k_convW<<<512, 256, 0, stream>>>(W, Wb);
  k_colstats<<<dim3(1, 128, 2), dim3(64, 8), 0, stream>>>(zb1, zb2, csum, csumsq);
  k_vloss<<<4, 256, 0, stream>>>(csum, csumsq, scal);
  k_gram<<<dim3(36, 1, 32), 256, 0, stream>>>(zb1, zb2, Gpart);
  k_covreduce<<<dim3(36 * 16, 2), 256, 0, stream>>>(Gpart, csum, scal);
  k_logits<<<dim3(128, 16, 2), 256, 0, stream>>>(zn1, zn2, Wb, L1, L2, rowsum);
  k_sink<<<dim3(512, 2), 256, 0, stream>>>(L1, L2, rowsum, 0);
  k_sink<<<dim3(512, 2), 256, 0, stream>>>(L1, L2, rowsum, 1);
  k_final<<<1024, 256, 0, stream>>>(L1, L2, rowsum, probsum, counts, scal);
  k_combine<<<1, 256, 0, stream>>>(scal, probsum, counts, (float*)d_out);
}